// Round 3
// baseline (262.205 us; speedup 1.0000x reference)
//
#include <hip/hip_runtime.h>
#include <hip/hip_bf16.h>
#include <limits.h>

// Problem constants (from reference)
#define BB   4
#define NN   2048
#define CC   512
#define TSZ  9
#define TSTEP 6
#define TCUT 2
#define GRIDW 120
#define NCELL (GRIDW * GRIDW)
#define TILE_ELEMS (CC * TSZ * TSZ)      // 41472
#define TILE_F4    (TILE_ELEMS / 4)      // 10368
#define OUT_PER_TILE (TILE_ELEMS + 1)    // 41473 (f_ns entry + tile)
#define MAXTILES (4 * 21 * 21)           // 1764

// ---------------- Kernel 1: init cellmap ----------------
__global__ void init_kernel(int* __restrict__ cellmap) {
    int i = blockIdx.x * blockDim.x + threadIdx.x;
    if (i < BB * NCELL) cellmap[i] = -1;
}

// ---------------- Kernel 2: scatter points (no atomics) ----------------
__global__ void scatter_kernel(const int* __restrict__ ys, const int* __restrict__ xs,
                               int* __restrict__ cellmap) {
    int i = blockIdx.x * blockDim.x + threadIdx.x;
    if (i >= BB * NN) return;
    int b = i >> 11;                      // i / NN
    int y = ys[i], x = xs[i];
    if (y < 0) return;                    // reference filters ys > -1
    cellmap[b * NCELL + y * GRIDW + x] = i - b * NN;   // point index within batch
}

// ---------------- Kernel 3: bbox + select + compaction + ntile table ----------------
// Single block, 512 threads. Tiles per batch <= 21*21 = 441 < 512.
// Produces: f_ns (K floats) and ntile[k][81] = global point index (b*NN+n) or -1.
__global__ __launch_bounds__(512) void select_kernel(
        const int* __restrict__ ys, const int* __restrict__ xs,
        const int* __restrict__ cellmap,
        int* __restrict__ ntile, float* __restrict__ f_ns) {
    __shared__ int s_off;
    __shared__ int s_wave[8];
    __shared__ int s_red[8][4];
    __shared__ int s_bbox[4];
    __shared__ int s_tinfo[MAXTILES];     // packed (b<<16)|(gy0<<8)|gx0
    const int tid = threadIdx.x;
    const int lane = tid & 63;
    const int wid = tid >> 6;
    if (tid == 0) s_off = 0;

    for (int b = 0; b < BB; ++b) {
        // ---- bbox reduction over this batch's 2048 points ----
        int ymin = INT_MAX, ymax = INT_MIN, xmin = INT_MAX, xmax = INT_MIN;
        for (int j = tid; j < NN; j += 512) {
            int y = ys[b * NN + j], x = xs[b * NN + j];
            if (y > -1) {
                ymin = min(ymin, y); ymax = max(ymax, y);
                xmin = min(xmin, x); xmax = max(xmax, x);
            }
        }
        #pragma unroll
        for (int off = 32; off; off >>= 1) {
            ymin = min(ymin, __shfl_xor(ymin, off));
            ymax = max(ymax, __shfl_xor(ymax, off));
            xmin = min(xmin, __shfl_xor(xmin, off));
            xmax = max(xmax, __shfl_xor(xmax, off));
        }
        if (lane == 0) {
            s_red[wid][0] = ymin; s_red[wid][1] = ymax;
            s_red[wid][2] = xmin; s_red[wid][3] = xmax;
        }
        __syncthreads();
        if (tid == 0) {
            int a = INT_MAX, bmx = INT_MIN, c = INT_MAX, d = INT_MIN;
            for (int w = 0; w < 8; ++w) {
                a = min(a, s_red[w][0]); bmx = max(bmx, s_red[w][1]);
                c = min(c, s_red[w][2]); d = max(d, s_red[w][3]);
            }
            s_bbox[0] = a; s_bbox[1] = bmx; s_bbox[2] = c; s_bbox[3] = d;
        }
        __syncthreads();
        ymin = s_bbox[0]; ymax = s_bbox[1]; xmin = s_bbox[2]; xmax = s_bbox[3];

        int nH = (ymax - ymin + 1) / TSTEP + 1;   // (H - T_SZ)//T_STEP + 1
        int nW = (xmax - xmin + 1) / TSTEP + 1;
        int nT = nH * nW;

        for (int base = 0; base < nT; base += 512) {
            int t = base + tid;
            bool m = false;
            int gy0 = 0, gx0 = 0;
            if (t < nT) {
                int ti = t / nW, tj = t - ti * nW;
                gy0 = ymin + ti * TSTEP;
                gx0 = xmin + tj * TSTEP;
                // center 5x5: rows gy0+2..gy0+6, cols gx0+2..gx0+6
                for (int dy = TCUT; dy <= TSZ - 1 - TCUT && !m; ++dy) {
                    int gy = gy0 + dy;
                    if (gy >= GRIDW) break;
                    const int* row = cellmap + b * NCELL + gy * GRIDW;
                    for (int dx = TCUT; dx <= TSZ - 1 - TCUT; ++dx) {
                        int gx = gx0 + dx;
                        if (gx >= GRIDW) break;
                        if (row[gx] >= 0) { m = true; break; }
                    }
                }
            }
            unsigned long long bal = __ballot(m);
            int lpre = __popcll(bal & ((lane == 0) ? 0ull : ((1ull << lane) - 1ull)));
            if (lane == 0) s_wave[wid] = (int)__popcll(bal);
            __syncthreads();
            if (tid == 0) {
                int acc = s_off;
                for (int w = 0; w < 8; ++w) { int v = s_wave[w]; s_wave[w] = acc; acc += v; }
                s_off = acc;
            }
            __syncthreads();
            if (m) {
                int idx = s_wave[wid] + lpre;
                s_tinfo[idx] = (b << 16) | (gy0 << 8) | gx0;
                f_ns[idx] = (float)b;
            }
            __syncthreads();
        }
    }

    // ---- ntile table: for each selected tile, the 81 global point indices ----
    const int Ktot = s_off;
    for (int e = tid; e < Ktot * 81; e += 512) {
        int k = e / 81, ce = e - k * 81;
        int info = s_tinfo[k];
        int b = info >> 16;
        int gy = ((info >> 8) & 255) + ce / 9;
        int gx = (info & 255) + ce - (ce / 9) * 9;
        int gn = -1;
        if (gy < GRIDW && gx < GRIDW) {
            int n = cellmap[b * NCELL + gy * GRIDW + gx];
            if (n >= 0) gn = b * NN + n;
        }
        ntile[e] = gn;
    }
}

// ---------------- Kernel 4: fill output tiles (flat, one float4/thread) ----------------
__global__ __launch_bounds__(256) void fill_kernel(
        const float* __restrict__ feats, const int* __restrict__ ntile,
        float* __restrict__ out_tiles, int total4) {
    int e4 = blockIdx.x * blockDim.x + threadIdx.x;
    if (e4 >= total4) return;
    int k = e4 / TILE_F4;
    int rem = e4 - k * TILE_F4;
    int idx = rem * 4;                 // element index within tile
    int c = idx / 81;
    int cell = idx - c * 81;
    const int* __restrict__ nt = ntile + k * 81;
    float v[4];
    #pragma unroll
    for (int j = 0; j < 4; ++j) {
        int cc = c, ce = cell + j;
        if (ce >= 81) { ce -= 81; ++cc; }
        int gn = nt[ce];
        v[j] = (gn >= 0) ? feats[(size_t)gn * CC + cc] : 0.0f;
    }
    ((float4*)out_tiles)[e4] = make_float4(v[0], v[1], v[2], v[3]);
}

// Scalar fallback if out_tiles isn't 16B-aligned (K % 4 != 0) — safety net.
__global__ __launch_bounds__(256) void fill_kernel_scalar(
        const float* __restrict__ feats, const int* __restrict__ ntile,
        float* __restrict__ out_tiles, int total) {
    int e = blockIdx.x * blockDim.x + threadIdx.x;
    if (e >= total) return;
    int k = e / TILE_ELEMS;
    int idx = e - k * TILE_ELEMS;
    int c = idx / 81;
    int ce = idx - c * 81;
    int gn = ntile[k * 81 + ce];
    out_tiles[e] = (gn >= 0) ? feats[(size_t)gn * CC + c] : 0.0f;
}

extern "C" void kernel_launch(void* const* d_in, const int* in_sizes, int n_in,
                              void* d_out, int out_size, void* d_ws, size_t ws_size,
                              hipStream_t stream) {
    const float* feats = (const float*)d_in[0];
    const int* ys = (const int*)d_in[1];
    const int* xs = (const int*)d_in[2];
    float* out = (float*)d_out;

    char* ws = (char*)d_ws;
    int* cellmap = (int*)ws;                          // 4*14400 ints = 230400 B
    int* ntile = (int*)(ws + BB * NCELL * 4 + 256);   // K*81 ints (<= 571 KB)

    const int K = out_size / OUT_PER_TILE;            // number of selected tiles
    float* f_ns = out;                                // first K floats
    float* out_tiles = out + K;                       // K * 41472 floats

    {
        int n = BB * NCELL;
        init_kernel<<<(n + 255) / 256, 256, 0, stream>>>(cellmap);
    }
    {
        int n = BB * NN;
        scatter_kernel<<<(n + 255) / 256, 256, 0, stream>>>(ys, xs, cellmap);
    }
    select_kernel<<<1, 512, 0, stream>>>(ys, xs, cellmap, ntile, f_ns);

    if ((K & 3) == 0) {
        int total4 = K * TILE_F4;
        fill_kernel<<<(total4 + 255) / 256, 256, 0, stream>>>(feats, ntile, out_tiles, total4);
    } else {
        int total = K * TILE_ELEMS;
        fill_kernel_scalar<<<(total + 255) / 256, 256, 0, stream>>>(feats, ntile, out_tiles, total);
    }
}

// Round 4
// 82.925 us; speedup vs baseline: 3.1620x; 3.1620x over previous
//
#include <hip/hip_runtime.h>
#include <hip/hip_bf16.h>
#include <limits.h>

// Problem constants (from reference)
#define BB   4
#define NN   2048
#define CC   512
#define TSZ  9
#define TSTEP 6
#define TCUT 2
#define GRIDW 120
#define CMS  132                          // padded cellmap stride (rows & cols)
#define CMSZ (CMS * CMS)                  // per-batch padded cells
#define TILE_ELEMS (CC * TSZ * TSZ)       // 41472
#define OUT_PER_TILE (TILE_ELEMS + 1)     // 41473 (f_ns entry + tile)

// ---------------- Kernel 1: init padded cellmap to -1 ----------------
__global__ void init_kernel(int* __restrict__ cellmap) {
    int i = blockIdx.x * blockDim.x + threadIdx.x;
    if (i < BB * CMSZ) cellmap[i] = -1;
}

// ---------------- Kernel 2: scatter points (no atomics) ----------------
__global__ void scatter_kernel(const int* __restrict__ ys, const int* __restrict__ xs,
                               int* __restrict__ cellmap) {
    int i = blockIdx.x * blockDim.x + threadIdx.x;
    if (i >= BB * NN) return;
    int b = i >> 11;                      // i / NN
    int y = ys[i], x = xs[i];
    if (y < 0) return;                    // reference filters ys > -1
    cellmap[b * CMSZ + y * CMS + x] = i - b * NN;   // point index within batch
}

// ---------------- Kernel 3: bbox + select + ordered compaction ----------------
// Single block, 512 threads. Tiles per batch <= 21*21 = 441 < 512.
// Produces: f_ns (K floats) and tileinfo[k] = (b<<16)|(gy0<<8)|gx0.
__global__ __launch_bounds__(512) void select_kernel(
        const int* __restrict__ ys, const int* __restrict__ xs,
        const int* __restrict__ cellmap,
        int* __restrict__ tileinfo, float* __restrict__ f_ns) {
    __shared__ int s_off;
    __shared__ int s_wave[8];
    __shared__ int s_red[8][4];
    __shared__ int s_bbox[4];
    const int tid = threadIdx.x;
    const int lane = tid & 63;
    const int wid = tid >> 6;
    if (tid == 0) s_off = 0;

    for (int b = 0; b < BB; ++b) {
        // ---- bbox reduction over this batch's 2048 points ----
        int ymin = INT_MAX, ymax = INT_MIN, xmin = INT_MAX, xmax = INT_MIN;
        for (int j = tid; j < NN; j += 512) {
            int y = ys[b * NN + j], x = xs[b * NN + j];
            if (y > -1) {
                ymin = min(ymin, y); ymax = max(ymax, y);
                xmin = min(xmin, x); xmax = max(xmax, x);
            }
        }
        #pragma unroll
        for (int off = 32; off; off >>= 1) {
            ymin = min(ymin, __shfl_xor(ymin, off));
            ymax = max(ymax, __shfl_xor(ymax, off));
            xmin = min(xmin, __shfl_xor(xmin, off));
            xmax = max(xmax, __shfl_xor(xmax, off));
        }
        if (lane == 0) {
            s_red[wid][0] = ymin; s_red[wid][1] = ymax;
            s_red[wid][2] = xmin; s_red[wid][3] = xmax;
        }
        __syncthreads();
        if (tid == 0) {
            int a = INT_MAX, bmx = INT_MIN, c = INT_MAX, d = INT_MIN;
            for (int w = 0; w < 8; ++w) {
                a = min(a, s_red[w][0]); bmx = max(bmx, s_red[w][1]);
                c = min(c, s_red[w][2]); d = max(d, s_red[w][3]);
            }
            s_bbox[0] = a; s_bbox[1] = bmx; s_bbox[2] = c; s_bbox[3] = d;
        }
        __syncthreads();
        ymin = s_bbox[0]; ymax = s_bbox[1]; xmin = s_bbox[2]; xmax = s_bbox[3];

        int nH = (ymax - ymin + 1) / TSTEP + 1;   // (H - T_SZ)//T_STEP + 1
        int nW = (xmax - xmin + 1) / TSTEP + 1;
        int nT = nH * nW;

        for (int base = 0; base < nT; base += 512) {
            int t = base + tid;
            bool m = false;
            int gy0 = 0, gx0 = 0;
            if (t < nT) {
                int ti = t / nW, tj = t - ti * nW;
                gy0 = ymin + ti * TSTEP;
                gx0 = xmin + tj * TSTEP;
                // center 5x5: 25 independent loads (padded map -> no bounds checks)
                const int* __restrict__ base_p =
                    cellmap + b * CMSZ + (gy0 + TCUT) * CMS + (gx0 + TCUT);
                int acc = -1;
                #pragma unroll
                for (int dy = 0; dy < 5; ++dy)
                    #pragma unroll
                    for (int dx = 0; dx < 5; ++dx)
                        acc = max(acc, base_p[dy * CMS + dx]);
                m = (acc >= 0);
            }
            unsigned long long bal = __ballot(m);
            int lpre = __popcll(bal & ((1ull << lane) - 1ull));
            if (lane == 0) s_wave[wid] = (int)__popcll(bal);
            __syncthreads();
            if (tid == 0) {
                int acc = s_off;
                for (int w = 0; w < 8; ++w) { int v = s_wave[w]; s_wave[w] = acc; acc += v; }
                s_off = acc;
            }
            __syncthreads();
            if (m) {
                int idx = s_wave[wid] + lpre;
                tileinfo[idx] = (b << 16) | (gy0 << 8) | gx0;
                f_ns[idx] = (float)b;
            }
            __syncthreads();
        }
    }
}

// ---------------- Kernel 4: fill output tiles (per-tile LDS transpose) ----------------
// One block per tile, 256 threads. Coalesced point-slice reads -> LDS -> coalesced
// float4 stores. Channels processed in 8 chunks of 64.
__global__ __launch_bounds__(256) void fill_kernel(
        const float* __restrict__ feats, const int* __restrict__ cellmap,
        const int* __restrict__ tileinfo, float* __restrict__ out_tiles) {
    __shared__ int s_n[81];               // cell -> point index (or -1)
    __shared__ int s_list[81];            // compact occupied list: (n<<7)|ce
    __shared__ int s_wcnt[2];
    __shared__ int s_cnt;
    __shared__ float s_f[64][81];         // [channel-in-chunk][cell], 20.7 KB

    const int tid = threadIdx.x;
    const int lane = tid & 63;
    const int wid = tid >> 6;
    const int k = blockIdx.x;

    const int info = tileinfo[k];
    const int b = info >> 16;
    const int gy0 = (info >> 8) & 255;
    const int gx0 = info & 255;

    int n = -1;
    if (tid < 81) {
        int r = tid / 9, c = tid - r * 9;
        n = cellmap[b * CMSZ + (gy0 + r) * CMS + (gx0 + c)];
        s_n[tid] = n;
    }
    bool occ = (tid < 81) && (n >= 0);
    unsigned long long bal = __ballot(occ);
    int pre = __popcll(bal & ((1ull << lane) - 1ull));
    if (lane == 0 && wid < 2) s_wcnt[wid] = (int)__popcll(bal);
    __syncthreads();
    if (occ) {
        int idx = (wid == 1 ? s_wcnt[0] : 0) + pre;
        s_list[idx] = (n << 7) | tid;     // n<=2047 (11b) | cell (7b)
    }
    if (tid == 0) s_cnt = s_wcnt[0] + s_wcnt[1];
    __syncthreads();

    const int nk = s_cnt;
    const float* __restrict__ fb = feats + (size_t)b * (NN * CC);
    float* __restrict__ outk = out_tiles + (size_t)k * TILE_ELEMS;

    for (int cb = 0; cb < CC; cb += 64) {
        // load: occupied points' 64-channel slice (coalesced 256B per point)
        for (int e = tid; e < nk * 64; e += 256) {
            int slot = e >> 6, cp = e & 63;
            int pk = s_list[slot];
            int pn = pk >> 7, ce = pk & 127;
            s_f[cp][ce] = fb[pn * CC + cb + cp];
        }
        __syncthreads();
        // write: 64*81 = 5184 floats = 1296 float4, coalesced
        for (int f4 = tid; f4 < 1296; f4 += 256) {
            int idx = f4 * 4;
            int ci = idx / 81;
            int ce = idx - ci * 81;
            float v[4];
            #pragma unroll
            for (int j = 0; j < 4; ++j) {
                int cij = ci, cej = ce + j;
                if (cej >= 81) { cej -= 81; ++cij; }
                v[j] = (s_n[cej] >= 0) ? s_f[cij][cej] : 0.0f;
            }
            *(float4*)(outk + cb * 81 + idx) = make_float4(v[0], v[1], v[2], v[3]);
        }
        __syncthreads();
    }
}

extern "C" void kernel_launch(void* const* d_in, const int* in_sizes, int n_in,
                              void* d_out, int out_size, void* d_ws, size_t ws_size,
                              hipStream_t stream) {
    const float* feats = (const float*)d_in[0];
    const int* ys = (const int*)d_in[1];
    const int* xs = (const int*)d_in[2];
    float* out = (float*)d_out;

    char* ws = (char*)d_ws;
    int* cellmap = (int*)ws;                              // 4*132*132*4 = 278784 B
    int* tileinfo = (int*)(ws + BB * CMSZ * 4);           // K ints (<= ~7 KB)

    const int K = out_size / OUT_PER_TILE;                // number of selected tiles
    float* f_ns = out;                                    // first K floats
    float* out_tiles = out + K;                           // K * 41472 floats

    {
        int ncl = BB * CMSZ;
        init_kernel<<<(ncl + 255) / 256, 256, 0, stream>>>(cellmap);
    }
    {
        int npt = BB * NN;
        scatter_kernel<<<(npt + 255) / 256, 256, 0, stream>>>(ys, xs, cellmap);
    }
    select_kernel<<<1, 512, 0, stream>>>(ys, xs, cellmap, tileinfo, f_ns);
    fill_kernel<<<K, 256, 0, stream>>>(feats, cellmap, tileinfo, out_tiles);
}

// Round 5
// 77.040 us; speedup vs baseline: 3.4035x; 1.0764x over previous
//
#include <hip/hip_runtime.h>
#include <hip/hip_bf16.h>
#include <limits.h>

// Problem constants (from reference)
#define BB   4
#define NN   2048
#define CC   512
#define TSZ  9
#define TSTEP 6
#define TCUT 2
#define GRIDW 120
#define CMS  132                          // padded cellmap stride (rows & cols)
#define CMSZ (CMS * CMS)                  // per-batch padded cells
#define TILE_ELEMS (CC * TSZ * TSZ)       // 41472
#define OUT_PER_TILE (TILE_ELEMS + 1)     // 41473 (f_ns entry + tile)

// ---------------- Kernel 1: init padded cellmap to -1, bbox sentinels ----------------
__global__ void init_kernel(int* __restrict__ cellmap, int* __restrict__ bbox) {
    int i = blockIdx.x * blockDim.x + threadIdx.x;
    if (i < 16) bbox[i] = (i & 1) ? INT_MIN : INT_MAX;   // [ymin,ymax,xmin,xmax] x4
    if (i < BB * CMSZ) cellmap[i] = -1;
}

// ---------------- Kernel 2: scatter + wave-reduced bbox atomics ----------------
// Waves never span batches (NN % 64 == 0), so one wave -> one batch.
__global__ void scatter_kernel(const int* __restrict__ ys, const int* __restrict__ xs,
                               int* __restrict__ cellmap, int* __restrict__ bbox) {
    int i = blockIdx.x * blockDim.x + threadIdx.x;
    if (i >= BB * NN) return;
    int b = i >> 11;                      // i / NN
    int y = ys[i], x = xs[i];
    int ymin = INT_MAX, ymax = INT_MIN, xmin = INT_MAX, xmax = INT_MIN;
    if (y > -1) {                         // reference filters ys > -1
        cellmap[b * CMSZ + y * CMS + x] = i - b * NN;   // point index within batch
        ymin = ymax = y; xmin = xmax = x;
    }
    #pragma unroll
    for (int off = 32; off; off >>= 1) {
        ymin = min(ymin, __shfl_xor(ymin, off));
        ymax = max(ymax, __shfl_xor(ymax, off));
        xmin = min(xmin, __shfl_xor(xmin, off));
        xmax = max(xmax, __shfl_xor(xmax, off));
    }
    if ((threadIdx.x & 63) == 0 && ymin != INT_MAX) {
        atomicMin(&bbox[b * 4 + 0], ymin);
        atomicMax(&bbox[b * 4 + 1], ymax);
        atomicMin(&bbox[b * 4 + 2], xmin);
        atomicMax(&bbox[b * 4 + 3], xmax);
    }
}

// ---------------- Kernel 3: select + ordered compaction ----------------
// Single block, 512 threads. nT per batch <= 21*21 = 441 < 512 (one pass/batch).
// Produces: f_ns (K floats) and tileinfo[k] = (b<<16)|(gy0<<8)|gx0.
__global__ __launch_bounds__(512) void select_kernel(
        const int* __restrict__ bbox, const int* __restrict__ cellmap,
        int* __restrict__ tileinfo, float* __restrict__ f_ns) {
    __shared__ int s_off;
    __shared__ int s_wave[8];
    const int tid = threadIdx.x;
    const int lane = tid & 63;
    const int wid = tid >> 6;
    if (tid == 0) s_off = 0;
    __syncthreads();

    for (int b = 0; b < BB; ++b) {
        int ymin = bbox[b * 4 + 0];
        int ymax = bbox[b * 4 + 1];
        int xmin = bbox[b * 4 + 2];
        int xmax = bbox[b * 4 + 3];
        int nH = (ymax - ymin + 1) / TSTEP + 1;   // (H - T_SZ)//T_STEP + 1
        int nW = (xmax - xmin + 1) / TSTEP + 1;
        int nT = nH * nW;

        for (int base = 0; base < nT; base += 512) {
            int t = base + tid;
            bool m = false;
            int gy0 = 0, gx0 = 0;
            if (t < nT) {
                int ti = t / nW, tj = t - ti * nW;
                gy0 = ymin + ti * TSTEP;
                gx0 = xmin + tj * TSTEP;
                // center 5x5: 25 independent loads (padded map -> no bounds checks)
                const int* __restrict__ base_p =
                    cellmap + b * CMSZ + (gy0 + TCUT) * CMS + (gx0 + TCUT);
                int acc = -1;
                #pragma unroll
                for (int dy = 0; dy < 5; ++dy)
                    #pragma unroll
                    for (int dx = 0; dx < 5; ++dx)
                        acc = max(acc, base_p[dy * CMS + dx]);
                m = (acc >= 0);
            }
            unsigned long long bal = __ballot(m);
            int lpre = __popcll(bal & ((1ull << lane) - 1ull));
            if (lane == 0) s_wave[wid] = (int)__popcll(bal);
            __syncthreads();
            if (tid == 0) {
                int acc = s_off;
                for (int w = 0; w < 8; ++w) { int v = s_wave[w]; s_wave[w] = acc; acc += v; }
                s_off = acc;
            }
            __syncthreads();
            if (m) {
                int idx = s_wave[wid] + lpre;
                tileinfo[idx] = (b << 16) | (gy0 << 8) | gx0;
                f_ns[idx] = (float)b;
            }
            __syncthreads();
        }
    }
}

// ---------------- Kernel 4: fill output tiles (per-tile LDS transpose) ----------------
// One block per tile, 256 threads. Coalesced point-slice reads -> LDS -> coalesced
// float4 stores. Channels processed in 8 chunks of 64.
__global__ __launch_bounds__(256) void fill_kernel(
        const float* __restrict__ feats, const int* __restrict__ cellmap,
        const int* __restrict__ tileinfo, float* __restrict__ out_tiles) {
    __shared__ int s_n[81];               // cell -> point index (or -1)
    __shared__ int s_list[81];            // compact occupied list: (n<<7)|ce
    __shared__ int s_wcnt[2];
    __shared__ int s_cnt;
    __shared__ float s_f[64][81];         // [channel-in-chunk][cell], 20.7 KB

    const int tid = threadIdx.x;
    const int lane = tid & 63;
    const int wid = tid >> 6;
    const int k = blockIdx.x;

    const int info = tileinfo[k];
    const int b = info >> 16;
    const int gy0 = (info >> 8) & 255;
    const int gx0 = info & 255;

    int n = -1;
    if (tid < 81) {
        int r = tid / 9, c = tid - r * 9;
        n = cellmap[b * CMSZ + (gy0 + r) * CMS + (gx0 + c)];
        s_n[tid] = n;
    }
    bool occ = (tid < 81) && (n >= 0);
    unsigned long long bal = __ballot(occ);
    int pre = __popcll(bal & ((1ull << lane) - 1ull));
    if (lane == 0 && wid < 2) s_wcnt[wid] = (int)__popcll(bal);
    __syncthreads();
    if (occ) {
        int idx = (wid == 1 ? s_wcnt[0] : 0) + pre;
        s_list[idx] = (n << 7) | tid;     // n<=2047 (11b) | cell (7b)
    }
    if (tid == 0) s_cnt = s_wcnt[0] + s_wcnt[1];
    __syncthreads();

    const int nk = s_cnt;
    const float* __restrict__ fb = feats + (size_t)b * (NN * CC);
    float* __restrict__ outk = out_tiles + (size_t)k * TILE_ELEMS;

    for (int cb = 0; cb < CC; cb += 64) {
        // load: occupied points' 64-channel slice (coalesced 256B per point)
        for (int e = tid; e < nk * 64; e += 256) {
            int slot = e >> 6, cp = e & 63;
            int pk = s_list[slot];
            int pn = pk >> 7, ce = pk & 127;
            s_f[cp][ce] = fb[pn * CC + cb + cp];
        }
        __syncthreads();
        // write: 64*81 = 5184 floats = 1296 float4, coalesced
        for (int f4 = tid; f4 < 1296; f4 += 256) {
            int idx = f4 * 4;
            int ci = idx / 81;
            int ce = idx - ci * 81;
            float v[4];
            #pragma unroll
            for (int j = 0; j < 4; ++j) {
                int cij = ci, cej = ce + j;
                if (cej >= 81) { cej -= 81; ++cij; }
                v[j] = (s_n[cej] >= 0) ? s_f[cij][cej] : 0.0f;
            }
            *(float4*)(outk + cb * 81 + idx) = make_float4(v[0], v[1], v[2], v[3]);
        }
        __syncthreads();
    }
}

extern "C" void kernel_launch(void* const* d_in, const int* in_sizes, int n_in,
                              void* d_out, int out_size, void* d_ws, size_t ws_size,
                              hipStream_t stream) {
    const float* feats = (const float*)d_in[0];
    const int* ys = (const int*)d_in[1];
    const int* xs = (const int*)d_in[2];
    float* out = (float*)d_out;

    char* ws = (char*)d_ws;
    int* cellmap = (int*)ws;                              // 4*132*132*4 = 278784 B
    int* bbox = (int*)(ws + BB * CMSZ * 4);               // 16 ints
    int* tileinfo = (int*)(ws + BB * CMSZ * 4 + 256);     // K ints (<= ~7 KB)

    const int K = out_size / OUT_PER_TILE;                // number of selected tiles
    float* f_ns = out;                                    // first K floats
    float* out_tiles = out + K;                           // K * 41472 floats

    {
        int ncl = BB * CMSZ;
        init_kernel<<<(ncl + 255) / 256, 256, 0, stream>>>(cellmap, bbox);
    }
    {
        int npt = BB * NN;
        scatter_kernel<<<(npt + 255) / 256, 256, 0, stream>>>(ys, xs, cellmap, bbox);
    }
    select_kernel<<<1, 512, 0, stream>>>(bbox, cellmap, tileinfo, f_ns);
    fill_kernel<<<K, 256, 0, stream>>>(feats, cellmap, tileinfo, out_tiles);
}

// Round 6
// 73.954 us; speedup vs baseline: 3.5455x; 1.0417x over previous
//
#include <hip/hip_runtime.h>
#include <hip/hip_bf16.h>
#include <limits.h>

// Problem constants (from reference)
#define BB   4
#define NN   2048
#define CC   512
#define TSZ  9
#define TSTEP 6
#define TCUT 2
#define GRIDW 120
#define CMS  132                          // padded cellmap stride (rows & cols)
#define CMSZ (CMS * CMS)                  // per-batch padded cells
#define TILE_ELEMS (CC * TSZ * TSZ)       // 41472
#define OUT_PER_TILE (TILE_ELEMS + 1)     // 41473 (f_ns entry + tile)

// ---------------- Kernel 1: init padded cellmap to -1 (int4), bbox sentinels ----------------
__global__ void init_kernel(int4* __restrict__ cellmap4, int* __restrict__ bbox) {
    int i = blockIdx.x * blockDim.x + threadIdx.x;
    if (i < 16) bbox[i] = (i & 1) ? INT_MIN : INT_MAX;   // [ymin,ymax,xmin,xmax] x4
    if (i < BB * CMSZ / 4) cellmap4[i] = make_int4(-1, -1, -1, -1);
}

// ---------------- Kernel 2: scatter + wave-reduced bbox atomics ----------------
// Waves never span batches (NN % 64 == 0), so one wave -> one batch.
__global__ void scatter_kernel(const int* __restrict__ ys, const int* __restrict__ xs,
                               int* __restrict__ cellmap, int* __restrict__ bbox) {
    int i = blockIdx.x * blockDim.x + threadIdx.x;
    if (i >= BB * NN) return;
    int b = i >> 11;                      // i / NN
    int y = ys[i], x = xs[i];
    int ymin = INT_MAX, ymax = INT_MIN, xmin = INT_MAX, xmax = INT_MIN;
    if (y > -1) {                         // reference filters ys > -1
        cellmap[b * CMSZ + y * CMS + x] = i - b * NN;   // point index within batch
        ymin = ymax = y; xmin = xmax = x;
    }
    #pragma unroll
    for (int off = 32; off; off >>= 1) {
        ymin = min(ymin, __shfl_xor(ymin, off));
        ymax = max(ymax, __shfl_xor(ymax, off));
        xmin = min(xmin, __shfl_xor(xmin, off));
        xmax = max(xmax, __shfl_xor(xmax, off));
    }
    if ((threadIdx.x & 63) == 0 && ymin != INT_MAX) {
        atomicMin(&bbox[b * 4 + 0], ymin);
        atomicMax(&bbox[b * 4 + 1], ymax);
        atomicMin(&bbox[b * 4 + 2], xmin);
        atomicMax(&bbox[b * 4 + 3], xmax);
    }
}

// ---------------- Kernel 3: select + ordered compaction ----------------
// Single block, 512 threads. nT per batch <= 21*21 = 441 < 512 (one pass/batch).
// Produces: f_ns (K floats) and tileinfo[k] = (b<<16)|(gy0<<8)|gx0.
__global__ __launch_bounds__(512) void select_kernel(
        const int* __restrict__ bbox, const int* __restrict__ cellmap,
        int* __restrict__ tileinfo, float* __restrict__ f_ns) {
    __shared__ int s_off;
    __shared__ int s_wave[8];
    const int tid = threadIdx.x;
    const int lane = tid & 63;
    const int wid = tid >> 6;
    if (tid == 0) s_off = 0;
    __syncthreads();

    for (int b = 0; b < BB; ++b) {
        int ymin = bbox[b * 4 + 0];
        int ymax = bbox[b * 4 + 1];
        int xmin = bbox[b * 4 + 2];
        int xmax = bbox[b * 4 + 3];
        int nH = (ymax - ymin + 1) / TSTEP + 1;   // (H - T_SZ)//T_STEP + 1
        int nW = (xmax - xmin + 1) / TSTEP + 1;
        int nT = nH * nW;

        for (int base = 0; base < nT; base += 512) {
            int t = base + tid;
            bool m = false;
            int gy0 = 0, gx0 = 0;
            if (t < nT) {
                int ti = t / nW, tj = t - ti * nW;
                gy0 = ymin + ti * TSTEP;
                gx0 = xmin + tj * TSTEP;
                // center 5x5: 25 independent loads (padded map -> no bounds checks)
                const int* __restrict__ base_p =
                    cellmap + b * CMSZ + (gy0 + TCUT) * CMS + (gx0 + TCUT);
                int acc = -1;
                #pragma unroll
                for (int dy = 0; dy < 5; ++dy)
                    #pragma unroll
                    for (int dx = 0; dx < 5; ++dx)
                        acc = max(acc, base_p[dy * CMS + dx]);
                m = (acc >= 0);
            }
            unsigned long long bal = __ballot(m);
            int lpre = __popcll(bal & ((1ull << lane) - 1ull));
            if (lane == 0) s_wave[wid] = (int)__popcll(bal);
            __syncthreads();
            if (tid == 0) {
                int acc = s_off;
                for (int w = 0; w < 8; ++w) { int v = s_wave[w]; s_wave[w] = acc; acc += v; }
                s_off = acc;
            }
            __syncthreads();
            if (m) {
                int idx = s_wave[wid] + lpre;
                tileinfo[idx] = (b << 16) | (gy0 << 8) | gx0;
                f_ns[idx] = (float)b;
            }
            __syncthreads();
        }
    }
}

// ---------------- Kernel 4: fill output tiles ----------------
// One block per tile, 256 threads. Pre-zeroed LDS chunk buffer; per 64-channel
// chunk: float4 gather of occupied point slices -> LDS, then a flat
// conflict-free float4 LDS->global copy (LDS layout == output layout).
__global__ __launch_bounds__(256) void fill_kernel(
        const float* __restrict__ feats, const int* __restrict__ cellmap,
        const int* __restrict__ tileinfo, float* __restrict__ out_tiles) {
    __shared__ int s_list[81];            // compact occupied list: (n<<7)|ce
    __shared__ int s_wcnt[2];
    __shared__ int s_cnt;
    __shared__ __align__(16) float s_f[64 * 81];   // flat == output order, 20.7 KB

    const int tid = threadIdx.x;
    const int lane = tid & 63;
    const int wid = tid >> 6;
    const int k = blockIdx.x;

    const int info = tileinfo[k];
    const int b = info >> 16;
    const int gy0 = (info >> 8) & 255;
    const int gx0 = info & 255;

    // zero the chunk buffer once; unoccupied cells stay 0 across all chunks
    const float4 z = make_float4(0.f, 0.f, 0.f, 0.f);
    for (int f4 = tid; f4 < 1296; f4 += 256) ((float4*)s_f)[f4] = z;

    int n = -1;
    if (tid < 81) {
        int r = tid / 9, c = tid - r * 9;
        n = cellmap[b * CMSZ + (gy0 + r) * CMS + (gx0 + c)];
    }
    bool occ = (tid < 81) && (n >= 0);
    unsigned long long bal = __ballot(occ);
    int pre = __popcll(bal & ((1ull << lane) - 1ull));
    if (lane == 0 && wid < 2) s_wcnt[wid] = (int)__popcll(bal);
    __syncthreads();
    if (occ) {
        int idx = (wid == 1 ? s_wcnt[0] : 0) + pre;
        s_list[idx] = (n << 7) | tid;     // n<=2047 (11b) | cell (7b)
    }
    if (tid == 0) s_cnt = s_wcnt[0] + s_wcnt[1];
    __syncthreads();

    const int nk = s_cnt;
    const float* __restrict__ fb = feats + (size_t)b * (NN * CC);
    float* __restrict__ outk = out_tiles + (size_t)k * TILE_ELEMS;

    for (int cb = 0; cb < CC; cb += 64) {
        // load: occupied points' 64-channel slice, float4 per thread
        for (int e = tid; e < nk * 16; e += 256) {
            int slot = e >> 4, q = e & 15;
            int pk = s_list[slot];
            int pn = pk >> 7, ce = pk & 127;
            float4 v = *(const float4*)(fb + pn * CC + cb + q * 4);
            s_f[(q * 4 + 0) * 81 + ce] = v.x;
            s_f[(q * 4 + 1) * 81 + ce] = v.y;
            s_f[(q * 4 + 2) * 81 + ce] = v.z;
            s_f[(q * 4 + 3) * 81 + ce] = v.w;
        }
        __syncthreads();
        // flat copy: 1296 float4, conflict-free ds_read_b128, coalesced stores
        float* __restrict__ outc = outk + cb * 81;
        for (int f4 = tid; f4 < 1296; f4 += 256) {
            float4 v = ((const float4*)s_f)[f4];
            *(float4*)(outc + f4 * 4) = v;
        }
        __syncthreads();
    }
}

extern "C" void kernel_launch(void* const* d_in, const int* in_sizes, int n_in,
                              void* d_out, int out_size, void* d_ws, size_t ws_size,
                              hipStream_t stream) {
    const float* feats = (const float*)d_in[0];
    const int* ys = (const int*)d_in[1];
    const int* xs = (const int*)d_in[2];
    float* out = (float*)d_out;

    char* ws = (char*)d_ws;
    int* cellmap = (int*)ws;                              // 4*132*132*4 = 278784 B
    int* bbox = (int*)(ws + BB * CMSZ * 4);               // 16 ints
    int* tileinfo = (int*)(ws + BB * CMSZ * 4 + 256);     // K ints (<= ~7 KB)

    const int K = out_size / OUT_PER_TILE;                // number of selected tiles
    float* f_ns = out;                                    // first K floats
    float* out_tiles = out + K;                           // K * 41472 floats

    {
        int n4 = BB * CMSZ / 4;
        init_kernel<<<(n4 + 255) / 256, 256, 0, stream>>>((int4*)cellmap, bbox);
    }
    {
        int npt = BB * NN;
        scatter_kernel<<<(npt + 255) / 256, 256, 0, stream>>>(ys, xs, cellmap, bbox);
    }
    select_kernel<<<1, 512, 0, stream>>>(bbox, cellmap, tileinfo, f_ns);
    fill_kernel<<<K, 256, 0, stream>>>(feats, cellmap, tileinfo, out_tiles);
}